// Round 4
// baseline (18.366 us; speedup 1.0000x reference)
//
#include <hip/hip_runtime.h>

namespace {
constexpr int IC = 8, IH = 28, IW = 28;
constexpr int OC = 16, KH = 3, KW = 3;
constexpr int OH = 28, OW = 28;
constexpr int BATCH = 64;
constexpr int XIN  = IC * IH * IW;   // 6272
constexpr int XOUT = OC * OH * OW;   // 12544
constexpr int PIH = IH + 2, PIW = IW + 2;   // 30x30 zero-padded image
constexpr int CSZ = PIH * PIW;       // 900 floats per channel
constexpr int PSZ = IC * CSZ;        // 7200 floats = 28.8 KB
constexpr int KSZ = IC * KH * KW;    // 72 taps per output channel
constexpr int THREADS = 256;
constexpr int NV4 = XIN / 4;         // 1568 float4 per image
}

// weight is the Toeplitz expansion of a 16x8x3x3 conv kernel (stride 1, pad 1):
// kernel[oc,ic,ky,kx] = weight[oc*784 + 14*28+14, ic*784 + (13+ky)*28 + (13+kx)]
// (interior output point oy=ox=14). 144 taps fetched by one predicated
// lane-parallel load (R3 lesson: scalarized s_loads serialize — don't).
// Each block serves 2 output channels: one staged image feeds two FMA chains.
__global__ __launch_bounds__(THREADS) void conv2d_toeplitz_kernel(
    const float* __restrict__ x, const float* __restrict__ w,
    const float* __restrict__ bias, float* __restrict__ out)
{
    __shared__ float xs[PSZ];
    __shared__ float ks[2 * KSZ];
    __shared__ float bs[2];

    const int tid = threadIdx.x;
    const int b   = blockIdx.x >> 3;        // 64 batches
    const int oc0 = (blockIdx.x & 7) * 2;   // oc pair {oc0, oc0+1}

    // ---- issue ALL global loads first (latency hides under halo zeroing) ----
    // taps + biases: one predicated lane-parallel load (146 lanes)
    float tv = 0.0f;
    if (tid < 2 * KSZ + 2) {
        if (tid < 2 * KSZ) {
            int oc = oc0 + (tid >= KSZ);
            int t  = tid - (tid >= KSZ ? KSZ : 0);
            int ic = t / (KH * KW);
            int kr = t - ic * (KH * KW);
            int ky = kr / KW;
            int kx = kr - ky * KW;
            int row = oc * (OH * OW) + 14 * OW + 14;
            int col = ic * (IH * IW) + (13 + ky) * IW + (13 + kx);
            tv = w[(long)row * XIN + col];
        } else {
            tv = bias[(oc0 + (tid - 2 * KSZ)) * (OH * OW)];
        }
    }
    // staged image as float4 (rows are 7 aligned groups of 4, never cross rows)
    const float4* xb4 = reinterpret_cast<const float4*>(x + b * XIN);
    float4 v[7];
    #pragma unroll
    for (int k = 0; k < 7; ++k) {
        int i = tid + k * THREADS;
        if (i < NV4) v[k] = xb4[i];
    }

    // ---- zero ONLY the halo (disjoint from interior: no barrier needed) ----
    // 116 halo cells per channel: top row 30, bottom row 30, left 28, right 28
    for (int i = tid; i < IC * 116; i += THREADS) {
        int ic = i / 116;
        int h  = i - ic * 116;
        int cell;
        if (h < 60)      cell = (h < 30) ? h : (29 * PIW + (h - 30));
        else if (h < 88) cell = (h - 59) * PIW;           // left col, rows 1..28
        else             cell = (h - 87) * PIW + (PIW-1); // right col, rows 1..28
        xs[ic * CSZ + cell] = 0.0f;
    }

    // ---- write staged data into the padded interior ----
    #pragma unroll
    for (int k = 0; k < 7; ++k) {
        int i = tid + k * THREADS;
        if (i < NV4) {
            int ic  = i / 196;            // 196 float4 per channel
            int r   = i - ic * 196;
            int row = r / 7;
            int cf  = (r - row * 7) * 7 == 0 ? (r - row * 7) * 4 : (r - row * 7) * 4; // (r%7)*4
            int dst = ic * CSZ + (row + 1) * PIW + (cf + 1);
            xs[dst]     = v[k].x;
            xs[dst + 1] = v[k].y;
            xs[dst + 2] = v[k].z;
            xs[dst + 3] = v[k].w;
        }
    }
    if (tid < 2 * KSZ)          ks[tid] = tv;
    else if (tid < 2 * KSZ + 2) bs[tid - 2 * KSZ] = tv;

    __syncthreads();   // the ONLY barrier

    // ---- 196 threads x 4 consecutive outputs x 2 oc (28 = 7 groups of 4) ----
    if (tid < 196) {
        const int oy = tid / 7;
        const int ox = (tid - oy * 7) * 4;
        float a0 = bs[0], a1 = bs[0], a2 = bs[0], a3 = bs[0];
        float c0 = bs[1], c1 = bs[1], c2 = bs[1], c3 = bs[1];
        #pragma unroll
        for (int ic = 0; ic < IC; ++ic) {
            #pragma unroll
            for (int ky = 0; ky < KH; ++ky) {
                const float* xr = &xs[ic * CSZ + (oy + ky) * PIW + ox];
                const float x0 = xr[0], x1 = xr[1], x2 = xr[2];
                const float x3 = xr[3], x4 = xr[4], x5 = xr[5];
                const float* ka = &ks[ic * (KH * KW) + ky * KW];
                const float k0 = ka[0], k1 = ka[1], k2 = ka[2];
                const float* kb = &ks[KSZ + ic * (KH * KW) + ky * KW];
                const float m0 = kb[0], m1 = kb[1], m2 = kb[2];
                a0 = fmaf(x2, k2, fmaf(x1, k1, fmaf(x0, k0, a0)));
                a1 = fmaf(x3, k2, fmaf(x2, k1, fmaf(x1, k0, a1)));
                a2 = fmaf(x4, k2, fmaf(x3, k1, fmaf(x2, k0, a2)));
                a3 = fmaf(x5, k2, fmaf(x4, k1, fmaf(x3, k0, a3)));
                c0 = fmaf(x2, m2, fmaf(x1, m1, fmaf(x0, m0, c0)));
                c1 = fmaf(x3, m2, fmaf(x2, m1, fmaf(x1, m0, c1)));
                c2 = fmaf(x4, m2, fmaf(x3, m1, fmaf(x2, m0, c2)));
                c3 = fmaf(x5, m2, fmaf(x4, m1, fmaf(x3, m0, c3)));
            }
        }
        // out index: b*12544 + oc*784 + oy*28 + ox; ox % 4 == 0 -> 16B aligned
        float* ob = out + (long)b * XOUT + oc0 * (OH * OW) + oy * OW + ox;
        *reinterpret_cast<float4*>(ob)               = make_float4(a0, a1, a2, a3);
        *reinterpret_cast<float4*>(ob + (OH * OW))   = make_float4(c0, c1, c2, c3);
    }
}

extern "C" void kernel_launch(void* const* d_in, const int* in_sizes, int n_in,
                              void* d_out, int out_size, void* d_ws, size_t ws_size,
                              hipStream_t stream) {
    const float* x    = (const float*)d_in[0];   // enc_x  [64, 6272] f32
    const float* w    = (const float*)d_in[1];   // weight [12544, 6272] f32 (Toeplitz)
    const float* bias = (const float*)d_in[2];   // bias   [12544] f32 (repeat per oc)
    float* out = (float*)d_out;                  // [64, 12544] f32

    conv2d_toeplitz_kernel<<<dim3(BATCH * OC / 2), THREADS, 0, stream>>>(x, w, bias, out);
}

// Round 5
// 13.067 us; speedup vs baseline: 1.4055x; 1.4055x over previous
//
#include <hip/hip_runtime.h>

namespace {
constexpr int IC = 8, IH = 28, IW = 28;
constexpr int OC = 16, KH = 3, KW = 3;
constexpr int OH = 28, OW = 28;
constexpr int BATCH = 64;
constexpr int XIN  = IC * IH * IW;   // 6272
constexpr int XOUT = OC * OH * OW;   // 12544
constexpr int PIH = IH + 2, PIW = IW + 2;   // 30x30 zero-padded image
constexpr int CSZ = PIH * PIW;       // 900 floats per channel
constexpr int PSZ = IC * CSZ;        // 7200 floats = 28.8 KB
constexpr int KSZ = IC * KH * KW;    // 72 taps per output channel
constexpr int THREADS = 256;
constexpr int NV4 = XIN / 4;         // 1568 float4 per image
}

// weight is the Toeplitz expansion of a 16x8x3x3 conv kernel (stride 1, pad 1).
// kernel[oc,ic,ky,kx] = weight[oc*784 + 14*28+14, ic*784 + (13+ky)*28 + (13+kx)]
// (interior output point oy=ox=14). 72 taps per block instead of 314 MB GEMM.
//
// R2 structure — best measured (13.07 us). R3 (taps->SGPR) and R4 (2 oc/block)
// both regressed: the kernel is per-block LATENCY-bound at a ~10us launch
// floor; lane-parallelism + 4 blocks/CU beats instruction-count reductions.
__global__ __launch_bounds__(THREADS) void conv2d_toeplitz_kernel(
    const float* __restrict__ x, const float* __restrict__ w,
    const float* __restrict__ bias, float* __restrict__ out)
{
    __shared__ float xs[PSZ];
    __shared__ float ks[KSZ];
    __shared__ float bs;

    const int tid = threadIdx.x;
    const int b   = blockIdx.x >> 4;   // 64 batches
    const int oc  = blockIdx.x & 15;   // 16 output channels

    // ---- issue ALL global loads first (latency hides under halo zeroing) ----
    // tap / bias load (one predicated lane-parallel load)
    float tv = 0.0f;
    if (tid < KSZ + 1) {
        if (tid < KSZ) {
            int ic = tid / (KH * KW);
            int kr = tid - ic * (KH * KW);
            int ky = kr / KW;
            int kx = kr - ky * KW;
            int row = oc * (OH * OW) + 14 * OW + 14;
            int col = ic * (IH * IW) + (13 + ky) * IW + (13 + kx);
            tv = w[(long)row * XIN + col];
        } else {
            tv = bias[oc * (OH * OW)];
        }
    }
    // staged image as float4 (rows are 7 aligned groups of 4, never cross rows)
    const float4* xb4 = reinterpret_cast<const float4*>(x + b * XIN);
    float4 v[7];
    #pragma unroll
    for (int k = 0; k < 7; ++k) {
        int i = tid + k * THREADS;
        if (i < NV4) v[k] = xb4[i];
    }

    // ---- zero ONLY the halo (disjoint from interior: no barrier needed) ----
    // 116 halo cells per channel: top row 30, bottom row 30, left 28, right 28
    for (int i = tid; i < IC * 116; i += THREADS) {
        int ic = i / 116;
        int h  = i - ic * 116;
        int cell;
        if (h < 60)      cell = (h < 30) ? h : (29 * PIW + (h - 30));
        else if (h < 88) cell = (h - 59) * PIW;           // left col, rows 1..28
        else             cell = (h - 87) * PIW + (PIW-1); // right col, rows 1..28
        xs[ic * CSZ + cell] = 0.0f;
    }

    // ---- write staged data into the padded interior ----
    #pragma unroll
    for (int k = 0; k < 7; ++k) {
        int i = tid + k * THREADS;
        if (i < NV4) {
            int ic  = i / 196;            // 196 float4 per channel
            int r   = i - ic * 196;
            int row = r / 7;
            int cf  = (r - row * 7) * 4;
            int dst = ic * CSZ + (row + 1) * PIW + (cf + 1);
            xs[dst]     = v[k].x;
            xs[dst + 1] = v[k].y;
            xs[dst + 2] = v[k].z;
            xs[dst + 3] = v[k].w;
        }
    }
    if (tid < KSZ) ks[tid] = tv;
    if (tid == KSZ) bs = tv;

    __syncthreads();   // the ONLY barrier

    // ---- 196 threads x 4 consecutive outputs (28 = 7 groups of 4) ----
    if (tid < 196) {
        const int oy = tid / 7;
        const int ox = (tid - oy * 7) * 4;
        const float b0 = bs;
        float a0 = b0, a1 = b0, a2 = b0, a3 = b0;
        #pragma unroll
        for (int ic = 0; ic < IC; ++ic) {
            #pragma unroll
            for (int ky = 0; ky < KH; ++ky) {
                const float* xr = &xs[ic * CSZ + (oy + ky) * PIW + ox];
                const float x0 = xr[0], x1 = xr[1], x2 = xr[2];
                const float x3 = xr[3], x4 = xr[4], x5 = xr[5];
                const float* kr = &ks[ic * (KH * KW) + ky * KW];
                const float k0 = kr[0], k1 = kr[1], k2 = kr[2];
                a0 = fmaf(x2, k2, fmaf(x1, k1, fmaf(x0, k0, a0)));
                a1 = fmaf(x3, k2, fmaf(x2, k1, fmaf(x1, k0, a1)));
                a2 = fmaf(x4, k2, fmaf(x3, k1, fmaf(x2, k0, a2)));
                a3 = fmaf(x5, k2, fmaf(x4, k1, fmaf(x3, k0, a3)));
            }
        }
        // out index: b*12544 + oc*784 + oy*28 + ox; ox % 4 == 0 -> 16B aligned
        float4* op = reinterpret_cast<float4*>(
            out + (long)b * XOUT + oc * (OH * OW) + oy * OW + ox);
        *op = make_float4(a0, a1, a2, a3);
    }
}

extern "C" void kernel_launch(void* const* d_in, const int* in_sizes, int n_in,
                              void* d_out, int out_size, void* d_ws, size_t ws_size,
                              hipStream_t stream) {
    const float* x    = (const float*)d_in[0];   // enc_x  [64, 6272] f32
    const float* w    = (const float*)d_in[1];   // weight [12544, 6272] f32 (Toeplitz)
    const float* bias = (const float*)d_in[2];   // bias   [12544] f32 (repeat per oc)
    float* out = (float*)d_out;                  // [64, 12544] f32

    conv2d_toeplitz_kernel<<<dim3(BATCH * OC), THREADS, 0, stream>>>(x, w, bias, out);
}